// Round 12
// baseline (172.978 us; speedup 1.0000x reference)
//
#include <hip/hip_runtime.h>
#include <cstdint>
#include <cstddef>

#define NN 100000
#define NE 3200000
#define D 128

#define NBUK  782           // ceil(NN/128): bucket = 128-node dst range
#define NBUKP 1024          // padded for partition scan (512*2)
#define BCAP  4608          // per-bucket capacity (mean 4092, +8 sigma)
#define EPB   5120          // edges per partition block (625 blocks)
#define PBLK  625           // partition blocks (first in grid: long pole)
#define CBLK  3125          // convert blocks (512 thr x 8 floats)

typedef __attribute__((ext_vector_type(8))) short bf16x8;
typedef __attribute__((ext_vector_type(4))) float f32x4;
typedef __attribute__((ext_vector_type(2))) float f32x2;

__device__ __forceinline__ unsigned short f2bf(float f) {
    unsigned int u = __float_as_uint(f);
    u += 0x7FFFu + ((u >> 16) & 1u);          // round-to-nearest-even
    return (unsigned short)(u >> 16);
}

__device__ __forceinline__ bf16x8 fp8x8_to_bf16x8(unsigned int lo, unsigned int hi) {
    const f32x2 p0 = __builtin_amdgcn_cvt_pk_f32_fp8(lo, false);
    const f32x2 p1 = __builtin_amdgcn_cvt_pk_f32_fp8(lo, true);
    const f32x2 p2 = __builtin_amdgcn_cvt_pk_f32_fp8(hi, false);
    const f32x2 p3 = __builtin_amdgcn_cvt_pk_f32_fp8(hi, true);
    union { unsigned int w[4]; bf16x8 v; } r;
    r.w[0] = (unsigned)f2bf(p0[0]) | ((unsigned)f2bf(p0[1]) << 16);
    r.w[1] = (unsigned)f2bf(p1[0]) | ((unsigned)f2bf(p1[1]) << 16);
    r.w[2] = (unsigned)f2bf(p2[0]) | ((unsigned)f2bf(p2[1]) << 16);
    r.w[3] = (unsigned)f2bf(p3[0]) | ((unsigned)f2bf(p3[1]) << 16);
    return r.v;
}

// ---------------------------------------------------------------------------
// k_all (512 threads): role by blockIdx (verified r10/r11):
//   [0,625)       1024-way radix partition of edges into 128-node buckets
//   [625,3750)    x fp32 -> xb bf16 AND xq fp8 e4m3   (reads x only)
//   [3750,3814)   pack W' = [Wl;Wr] into MFMA B-frag layout (verified r4)
// EPB 5120 (26.6KB LDS) -> 625 blocks, ~4/CU co-resident: 2.5x the latency
// hiding of r11's 250x61KB config, while 128-node buckets keep flush run
// length at 6.5 (r7's write-amp regression was run length 4.1).
// Edge word: (dst & 127) << 17 | src  (17-bit src, 7-bit local dst).
// ---------------------------------------------------------------------------
__global__ __launch_bounds__(512)
void k_all(const float* __restrict__ x,
           const int* __restrict__ ei,
           const float* __restrict__ Wl, const float* __restrict__ Wr,
           unsigned short* __restrict__ xb,
           unsigned char* __restrict__ xq,
           unsigned short* __restrict__ wf,
           unsigned int* __restrict__ gcur,
           unsigned int* __restrict__ ebuf)
{
    const int blk = blockIdx.x;
    const int t   = threadIdx.x;

    if (blk >= PBLK) {
        if (blk < PBLK + CBLK) {
            const size_t i8 = ((size_t)(blk - PBLK) * 512 + t) * 8;
            const float4 v0 = *reinterpret_cast<const float4*>(x + i8);
            const float4 v1 = *reinterpret_cast<const float4*>(x + i8 + 4);
            uint4 o;
            o.x = (unsigned)f2bf(v0.x) | ((unsigned)f2bf(v0.y) << 16);
            o.y = (unsigned)f2bf(v0.z) | ((unsigned)f2bf(v0.w) << 16);
            o.z = (unsigned)f2bf(v1.x) | ((unsigned)f2bf(v1.y) << 16);
            o.w = (unsigned)f2bf(v1.z) | ((unsigned)f2bf(v1.w) << 16);
            *reinterpret_cast<uint4*>(xb + i8) = o;
            int p0 = __builtin_amdgcn_cvt_pk_fp8_f32(v0.x, v0.y, 0, false);
            p0     = __builtin_amdgcn_cvt_pk_fp8_f32(v0.z, v0.w, p0, true);
            int p1 = __builtin_amdgcn_cvt_pk_fp8_f32(v1.x, v1.y, 0, false);
            p1     = __builtin_amdgcn_cvt_pk_fp8_f32(v1.z, v1.w, p1, true);
            uint2 q; q.x = (unsigned)p0; q.y = (unsigned)p1;
            *reinterpret_cast<uint2*>(xq + i8) = q;
        } else {
            const int tid  = (blk - PBLK - CBLK) * 512 + t;   // 32768 total
            const int j    = tid & 7;
            const int lane = (tid >> 3) & 63;
            const int tt   = (tid >> 9) & 7;
            const int kt   = tid >> 12;
            const int k    = kt * 32 + (lane >> 4) * 8 + j;
            const int cc   = tt * 16 + (lane & 15);
            const float v  = (k < D) ? Wl[k * D + cc] : Wr[(k - D) * D + cc];
            wf[tid] = f2bf(v);
        }
        return;
    }

    // ---- partition: block owns EPB=5120 edges ----
    __shared__ unsigned int staging[EPB];      // 20480 B
    __shared__ unsigned int hist[NBUKP];       // 4096 B
    __shared__ unsigned int partials[512];     // 2048 B

    const int e0 = blk * EPB;

    hist[t] = 0u; hist[t + 512] = 0u;
    __syncthreads();

    #pragma unroll
    for (int j = 0; j < 10; ++j) {
        const int d = ei[NE + e0 + j * 512 + t];
        atomicAdd(&hist[d >> 7], 1u);
    }
    __syncthreads();

    unsigned int c = hist[t * 2] + hist[t * 2 + 1];
    partials[t] = c;
    __syncthreads();
    for (int dstep = 1; dstep < 512; dstep <<= 1) {
        const unsigned int v = (t >= dstep) ? partials[t - dstep] : 0u;
        __syncthreads();
        partials[t] += v;
        __syncthreads();
    }
    unsigned int running = (t == 0) ? 0u : partials[t - 1];
    #pragma unroll
    for (int k = 0; k < 2; ++k) {
        running += hist[t * 2 + k];
        hist[t * 2 + k] = running;            // inclusive end
    }
    __syncthreads();

    #pragma unroll
    for (int j = 0; j < 10; ++j) {
        const int e = e0 + j * 512 + t;
        const int s = ei[e];
        const int d = ei[NE + e];
        const unsigned int pos = atomicSub(&hist[d >> 7], 1u) - 1u;
        staging[pos] = ((unsigned)(d & 127) << 17) | (unsigned)s;
    }
    __syncthreads();

    // flush: thread window [t*10, t*10+10), monotone bucket walk, uint2 pairs
    int i = t * 10;
    const int wEnd = i + 10;
    int lo = 0, hi = NBUKP - 1;
    while (lo < hi) {                          // largest b with start[b] <= i
        const int mid = (lo + hi + 1) >> 1;
        if ((int)hist[mid] <= i) lo = mid; else hi = mid - 1;
    }
    int bp = lo;
    while (i < wEnd) {
        while (bp + 1 < NBUKP && (int)hist[bp + 1] <= i) ++bp;
        const int bEnd = (bp + 1 < NBUKP) ? (int)hist[bp + 1] : EPB;
        const int runEnd = (wEnd < bEnd) ? wEnd : bEnd;
        const int len = runEnd - i;
        const unsigned int g = atomicAdd(&gcur[bp], (unsigned)len);
        if (g + (unsigned)len <= (unsigned)BCAP) {
            unsigned int dj = (unsigned)bp * BCAP + g;
            int k = 0;
            if ((dj & 1u) && k < len) { ebuf[dj] = staging[i + k]; ++k; ++dj; }
            for (; k + 1 < len; k += 2, dj += 2) {
                uint2 p; p.x = staging[i + k]; p.y = staging[i + k + 1];
                *reinterpret_cast<uint2*>(&ebuf[dj]) = p;
            }
            if (k < len) ebuf[dj] = staging[i + k];
        }
        i = runEnd;
    }
}

// ---------------------------------------------------------------------------
// k_gather (512 thr, 8 waves x 16 nodes = 128-node bucket): phases A-C
// verified r8-r11. wreg[9] keeps VGPR <= 64 -> 32 waves/CU. Writes the 128
// fp8 mean rows (16KB) into the bucket's OWN ebuf slot (18KB, dead after
// phase A). LDS 19.5 KB.
// ---------------------------------------------------------------------------
__global__ __launch_bounds__(512, 8)
void k_gather(const unsigned char* __restrict__ xq,
              const unsigned int* __restrict__ gcur,
              unsigned int* __restrict__ ebuf)
{
    __shared__ unsigned int ew[BCAP];          // 18432 B sorted edge words
    __shared__ unsigned int hcnt[128];
    __shared__ unsigned int hstart[129];

    const int t    = threadIdx.x;
    const int w    = t >> 6;
    const int lane = t & 63;
    const int b    = blockIdx.x;

    const unsigned int cntu = gcur[b];
    const int count = (int)(cntu < (unsigned)BCAP ? cntu : (unsigned)BCAP);
    const size_t bb = (size_t)b * BCAP;

    // A: register-stage + zero histogram (ebuf[b] is dead after this)
    unsigned int wreg[9];
    #pragma unroll
    for (int k = 0; k < 9; ++k) {
        const int i = t + k * 512;
        wreg[k] = (i < count) ? ebuf[bb + i] : 0xFFFFFFFFu;
    }
    if (t < 128) hcnt[t] = 0u;
    __syncthreads();

    // B1: histogram (one LDS atomic per edge)
    #pragma unroll
    for (int k = 0; k < 9; ++k)
        if (wreg[k] != 0xFFFFFFFFu) atomicAdd(&hcnt[wreg[k] >> 17], 1u);
    __syncthreads();

    // B2: two-wave inclusive scan of 128 counts -> hstart
    if (t < 128) {
        unsigned int p = hcnt[t];
        #pragma unroll
        for (int d = 1; d < 64; d <<= 1) {
            const unsigned int v = __shfl_up(p, d, 64);
            if (lane >= d) p += v;
        }
        hstart[t + 1] = p;
        if (t == 0) hstart[0] = 0u;
    }
    __syncthreads();
    if (t >= 64 && t < 128) hstart[t + 1] += hstart[64];
    __syncthreads();
    if (t < 128) hcnt[t] = hstart[t];
    __syncthreads();

    // B3: scatter into sorted ew[]
    #pragma unroll
    for (int k = 0; k < 9; ++k) {
        const unsigned int wv = wreg[k];
        if (wv != 0xFFFFFFFFu) {
            const unsigned int pos = atomicAdd(&hcnt[wv >> 17], 1u);
            ew[pos] = wv;
        }
    }
    __syncthreads();

    // C: half-wave dual-row gather (r8-verified), fp8 mean -> ebuf slot
    const int half = lane >> 5;
    const int hl   = lane & 31;
    const size_t boff = (size_t)(hl << 2);

    for (int i = 0; i < 16; ++i) {
        const int n = w * 16 + i;
        const int s = (int)hstart[n];
        const int e = (int)hstart[n + 1];
        const int dg = e - s;
        float a0 = 0.f, a1 = 0.f, a2 = 0.f, a3 = 0.f;
        int c = s;
        for (; c + 8 <= e; c += 8) {
            unsigned int u[4];
            #pragma unroll
            for (int j = 0; j < 4; ++j) {
                const unsigned int wj = ew[c + 2 * j + half];
                u[j] = *reinterpret_cast<const unsigned int*>(
                    xq + ((size_t)(wj & 0x1FFFFu) << 7) + boff);
            }
            #pragma unroll
            for (int j = 0; j < 4; ++j) {
                const f32x2 p = __builtin_amdgcn_cvt_pk_f32_fp8(u[j], false);
                const f32x2 q = __builtin_amdgcn_cvt_pk_f32_fp8(u[j], true);
                a0 += p[0]; a1 += p[1]; a2 += q[0]; a3 += q[1];
            }
        }
        for (; c + 2 <= e; c += 2) {
            const unsigned int w0 = ew[c + half];
            const unsigned int u0 = *reinterpret_cast<const unsigned int*>(
                xq + ((size_t)(w0 & 0x1FFFFu) << 7) + boff);
            const f32x2 p = __builtin_amdgcn_cvt_pk_f32_fp8(u0, false);
            const f32x2 q = __builtin_amdgcn_cvt_pk_f32_fp8(u0, true);
            a0 += p[0]; a1 += p[1]; a2 += q[0]; a3 += q[1];
        }
        if (c < e && half == 0) {              // final odd edge, half 0 only
            const unsigned int w0 = ew[c];
            const unsigned int u0 = *reinterpret_cast<const unsigned int*>(
                xq + ((size_t)(w0 & 0x1FFFFu) << 7) + boff);
            const f32x2 p = __builtin_amdgcn_cvt_pk_f32_fp8(u0, false);
            const f32x2 q = __builtin_amdgcn_cvt_pk_f32_fp8(u0, true);
            a0 += p[0]; a1 += p[1]; a2 += q[0]; a3 += q[1];
        }
        a0 += __shfl_xor(a0, 32, 64);
        a1 += __shfl_xor(a1, 32, 64);
        a2 += __shfl_xor(a2, 32, 64);
        a3 += __shfl_xor(a3, 32, 64);
        const float inv = 1.0f / (float)(dg > 1 ? dg : 1);
        if (half == 0) {
            int pk = __builtin_amdgcn_cvt_pk_fp8_f32(a0 * inv, a1 * inv, 0, false);
            pk     = __builtin_amdgcn_cvt_pk_fp8_f32(a2 * inv, a3 * inv, pk, true);
            ebuf[bb + (unsigned)(n << 5) + (unsigned)hl] = (unsigned)pk;  // 128B/row
        }
    }
}

// ---------------------------------------------------------------------------
// k_gemm: one block per 64-node half of a bucket. Stage 64 fp8 mean rows
// from the bucket's ebuf slot into LDS, then r10/r11-verified MFMA GEMM
// [mean|x]@[Wl;Wr]+b -> LayerNorm -> exact GELU.
// ---------------------------------------------------------------------------
__global__ __launch_bounds__(256)
void k_gemm(const unsigned short* __restrict__ xb,
            const unsigned int* __restrict__ ebuf,
            const unsigned short* __restrict__ wf,
            const float* __restrict__ bl,
            const float* __restrict__ gamma,
            const float* __restrict__ beta,
            float* __restrict__ out)
{
    __shared__ unsigned char smean[64][136];   // 8704 B fp8 mean rows

    const int t    = threadIdx.x;
    const int w    = t >> 6;
    const int lane = t & 63;
    const int b    = blockIdx.x >> 1;
    const int h    = blockIdx.x & 1;
    const int nodeBase = b * 128 + h * 64;

    // stage: 2048 uints, coalesced global read -> strided LDS write
    const unsigned int* gm = ebuf + (size_t)b * BCAP + h * 2048;
    #pragma unroll
    for (int k = 0; k < 8; ++k) {
        const int idx = k * 256 + t;          // 0..2047
        const int row = idx >> 5;
        const int c4  = (idx & 31) << 2;
        *reinterpret_cast<unsigned int*>(&smean[row][c4]) = gm[idx];
    }
    __syncthreads();

    // MFMA GEMM, K = 256 = [mean(128) | x(128)] (verified r4/r10/r11)
    const int row  = lane & 15;
    const int kgrp = lane >> 4;
    const int node_r = nodeBase + w * 16 + row;
    const size_t xrow = (size_t)(node_r < NN ? node_r : NN - 1) << 7;

    f32x4 accr[8];
    const f32x4 zero = {0.f, 0.f, 0.f, 0.f};
    #pragma unroll
    for (int q = 0; q < 8; ++q) accr[q] = zero;

    #pragma unroll
    for (int kt = 0; kt < 8; ++kt) {
        bf16x8 a;
        if (kt < 4) {
            const uint2 m8 = *reinterpret_cast<const uint2*>(
                &smean[w * 16 + row][kt * 32 + kgrp * 8]);
            a = fp8x8_to_bf16x8(m8.x, m8.y);
        } else {
            a = *reinterpret_cast<const bf16x8*>(xb + xrow + (kt - 4) * 32 + kgrp * 8);
        }
        #pragma unroll
        for (int q = 0; q < 8; ++q) {
            const bf16x8 bfrag = *reinterpret_cast<const bf16x8*>(
                wf + (((kt * 8 + q) * 64 + lane) << 3));
            accr[q] = __builtin_amdgcn_mfma_f32_16x16x32_bf16(a, bfrag, accr[q], 0, 0, 0);
        }
    }

    // bias + LayerNorm + exact GELU + store
    const int col = lane & 15;
    float gv[8], bev[8], blv[8];
    #pragma unroll
    for (int q = 0; q < 8; ++q) {
        gv[q]  = gamma[q * 16 + col];
        bev[q] = beta[q * 16 + col];
        blv[q] = bl[q * 16 + col];
    }
    const float k2 = 0.70710678118654752f;
    #pragma unroll
    for (int r = 0; r < 4; ++r) {
        float p = 0.f, p2 = 0.f;
        #pragma unroll
        for (int q = 0; q < 8; ++q) {
            const float h2 = accr[q][r] + blv[q];
            p += h2; p2 += h2 * h2;
        }
        #pragma unroll
        for (int m = 1; m <= 8; m <<= 1) {
            p  += __shfl_xor(p,  m, 64);
            p2 += __shfl_xor(p2, m, 64);
        }
        const float mu   = p * (1.0f / 128.0f);
        const float var  = p2 * (1.0f / 128.0f) - mu * mu;
        const float rstd = rsqrtf(var + 1e-5f);
        const int node = nodeBase + w * 16 + kgrp * 4 + r;
        if (node < NN) {
            #pragma unroll
            for (int q = 0; q < 8; ++q) {
                const float hq = accr[q][r] + blv[q];
                const float y = (hq - mu) * rstd * gv[q] + bev[q];
                out[(size_t)node * D + q * 16 + col] = 0.5f * y * (1.0f + erff(y * k2));
            }
        }
    }
}

extern "C" void kernel_launch(void* const* d_in, const int* in_sizes, int n_in,
                              void* d_out, int out_size, void* d_ws, size_t ws_size,
                              hipStream_t stream)
{
    const float* x     = (const float*)d_in[0];
    const int*   ei    = (const int*)d_in[1];
    const float* Wl    = (const float*)d_in[2];
    const float* bl    = (const float*)d_in[3];
    const float* Wr    = (const float*)d_in[4];
    const float* gamma = (const float*)d_in[5];
    const float* beta  = (const float*)d_in[6];
    float* out = (float*)d_out;

    // ws layout: gcur 32K | ebuf 14.5M | xb 25.6M | xq 12.8M | wf 64K ~ 53MB
    char* wsp = (char*)d_ws;
    unsigned int*   gcur = (unsigned int*)(wsp + 0);
    unsigned int*   ebuf = (unsigned int*)(wsp + 32768);
    unsigned short* xb   = (unsigned short*)(wsp + 16416768);
    unsigned char*  xq   = (unsigned char*)(wsp + 42016768);
    unsigned short* wf   = (unsigned short*)(wsp + 54816768);

    hipMemsetAsync(gcur, 0, NBUKP * sizeof(unsigned int), stream);

    k_all<<<PBLK + CBLK + 64, 512, 0, stream>>>(x, ei, Wl, Wr, xb, xq, wf,
                                                gcur, ebuf);

    k_gather<<<NBUK, 512, 0, stream>>>(xq, gcur, ebuf);

    k_gemm<<<NBUK * 2, 256, 0, stream>>>(xb, ebuf, wf, bl, gamma, beta, out);
}

// Round 13
// 148.946 us; speedup vs baseline: 1.1613x; 1.1613x over previous
//
#include <hip/hip_runtime.h>
#include <cstdint>
#include <cstddef>

#define NN 100000
#define NE 3200000
#define D 128

#define NBUK  1563          // ceil(NN/64): bucket = 64-node dst range (r11)
#define NBUKP 2048          // padded for 1024-thr partition scan (2 bins/thr)
#define BCAP  2560          // per-bucket capacity (mean 2048, +11 sigma)
#define EPB   12800         // edges per partition block (250 blocks, r11)
#define PBLK  250           // partition blocks (first in grid: long pole)
#define CBLK  1563          // convert blocks (1024 thr x 8 floats, guarded)

typedef __attribute__((ext_vector_type(8))) short bf16x8;
typedef __attribute__((ext_vector_type(4))) float f32x4;
typedef __attribute__((ext_vector_type(2))) float f32x2;

__device__ __forceinline__ unsigned short f2bf(float f) {
    unsigned int u = __float_as_uint(f);
    u += 0x7FFFu + ((u >> 16) & 1u);          // round-to-nearest-even
    return (unsigned short)(u >> 16);
}

__device__ __forceinline__ bf16x8 fp8x8_to_bf16x8(unsigned int lo, unsigned int hi) {
    const f32x2 p0 = __builtin_amdgcn_cvt_pk_f32_fp8(lo, false);
    const f32x2 p1 = __builtin_amdgcn_cvt_pk_f32_fp8(lo, true);
    const f32x2 p2 = __builtin_amdgcn_cvt_pk_f32_fp8(hi, false);
    const f32x2 p3 = __builtin_amdgcn_cvt_pk_f32_fp8(hi, true);
    union { unsigned int w[4]; bf16x8 v; } r;
    r.w[0] = (unsigned)f2bf(p0[0]) | ((unsigned)f2bf(p0[1]) << 16);
    r.w[1] = (unsigned)f2bf(p1[0]) | ((unsigned)f2bf(p1[1]) << 16);
    r.w[2] = (unsigned)f2bf(p2[0]) | ((unsigned)f2bf(p2[1]) << 16);
    r.w[3] = (unsigned)f2bf(p3[0]) | ((unsigned)f2bf(p3[1]) << 16);
    return r.v;
}

// ---------------------------------------------------------------------------
// k_all (1024 threads): role by blockIdx:
//   [0,250)        1563-way radix partition, r11 geometry (EPB 12800,
//                  flush-run length 8.2) but 16 waves/block for latency
//                  hiding; dst staged in registers -> ei read once + src once
//   [250,1813)     x fp32 -> xq fp8 e4m3 ONLY (xb copy eliminated — k_gemm
//                  converts fp32->bf16 in registers)
//   [1813,1845)    pack W' = [Wl;Wr] into MFMA B-frag layout (verified r4)
// Edge word: (dst & 63) << 17 | src.
// ---------------------------------------------------------------------------
__global__ __launch_bounds__(1024)
void k_all(const float* __restrict__ x,
           const int* __restrict__ ei,
           const float* __restrict__ Wl, const float* __restrict__ Wr,
           unsigned char* __restrict__ xq,
           unsigned short* __restrict__ wf,
           unsigned int* __restrict__ gcur,
           unsigned int* __restrict__ ebuf)
{
    const int blk = blockIdx.x;
    const int t   = threadIdx.x;

    if (blk >= PBLK) {
        if (blk < PBLK + CBLK) {
            // ---- convert: fp8 copy of x only ----
            const size_t i8 = ((size_t)(blk - PBLK) * 1024 + t) * 8;
            if (i8 < (size_t)NN * D) {
                const float4 v0 = *reinterpret_cast<const float4*>(x + i8);
                const float4 v1 = *reinterpret_cast<const float4*>(x + i8 + 4);
                int p0 = __builtin_amdgcn_cvt_pk_fp8_f32(v0.x, v0.y, 0, false);
                p0     = __builtin_amdgcn_cvt_pk_fp8_f32(v0.z, v0.w, p0, true);
                int p1 = __builtin_amdgcn_cvt_pk_fp8_f32(v1.x, v1.y, 0, false);
                p1     = __builtin_amdgcn_cvt_pk_fp8_f32(v1.z, v1.w, p1, true);
                uint2 q; q.x = (unsigned)p0; q.y = (unsigned)p1;
                *reinterpret_cast<uint2*>(xq + i8) = q;
            }
        } else {
            // ---- wprep: W' -> MFMA B-frag layout (verified r4) ----
            const int tid  = (blk - PBLK - CBLK) * 1024 + t;   // 32768 total
            const int j    = tid & 7;
            const int lane = (tid >> 3) & 63;
            const int tt   = (tid >> 9) & 7;
            const int kt   = tid >> 12;
            const int k    = kt * 32 + (lane >> 4) * 8 + j;
            const int cc   = tt * 16 + (lane & 15);
            const float v  = (k < D) ? Wl[k * D + cc] : Wr[(k - D) * D + cc];
            wf[tid] = f2bf(v);
        }
        return;
    }

    // ---- partition: block owns EPB=12800 edges, 1024 threads ----
    __shared__ unsigned int staging[EPB];      // 51200 B
    __shared__ unsigned int hist[NBUKP];       // 8192 B
    __shared__ unsigned int partials[1024];    // 4096 B

    const int e0 = blk * EPB;

    hist[t] = 0u; hist[t + 1024] = 0u;
    __syncthreads();

    // histogram; stage dst in registers (ei dst half read ONCE)
    int dreg[13];
    #pragma unroll
    for (int j = 0; j < 13; ++j) {
        const int e = j * 1024 + t;
        if (e < EPB) {
            dreg[j] = ei[NE + e0 + e];
            atomicAdd(&hist[dreg[j] >> 6], 1u);
        }
    }
    __syncthreads();

    unsigned int c = hist[t * 2] + hist[t * 2 + 1];
    partials[t] = c;
    __syncthreads();
    for (int dstep = 1; dstep < 1024; dstep <<= 1) {
        const unsigned int v = (t >= dstep) ? partials[t - dstep] : 0u;
        __syncthreads();
        partials[t] += v;
        __syncthreads();
    }
    unsigned int running = (t == 0) ? 0u : partials[t - 1];
    #pragma unroll
    for (int k = 0; k < 2; ++k) {
        running += hist[t * 2 + k];
        hist[t * 2 + k] = running;            // inclusive end
    }
    __syncthreads();

    // scatter: read src only (dst already in dreg)
    #pragma unroll
    for (int j = 0; j < 13; ++j) {
        const int e = j * 1024 + t;
        if (e < EPB) {
            const int s = ei[e0 + e];
            const int d = dreg[j];
            const unsigned int pos = atomicSub(&hist[d >> 6], 1u) - 1u;
            staging[pos] = ((unsigned)(d & 63) << 17) | (unsigned)s;
        }
    }
    __syncthreads();

    // flush: window [(t*25)>>1, ((t+1)*25)>>1), monotone walk, uint2 pairs
    int i = (t * 25) >> 1;
    const int wEnd = ((t + 1) * 25) >> 1;
    int lo = 0, hi = NBUKP - 1;
    while (lo < hi) {                          // largest b with start[b] <= i
        const int mid = (lo + hi + 1) >> 1;
        if ((int)hist[mid] <= i) lo = mid; else hi = mid - 1;
    }
    int bp = lo;
    while (i < wEnd) {
        while (bp + 1 < NBUKP && (int)hist[bp + 1] <= i) ++bp;
        const int bEnd = (bp + 1 < NBUKP) ? (int)hist[bp + 1] : EPB;
        const int runEnd = (wEnd < bEnd) ? wEnd : bEnd;
        const int len = runEnd - i;
        const unsigned int g = atomicAdd(&gcur[bp], (unsigned)len);
        if (g + (unsigned)len <= (unsigned)BCAP) {
            unsigned int dj = (unsigned)bp * BCAP + g;
            int k = 0;
            if ((dj & 1u) && k < len) { ebuf[dj] = staging[i + k]; ++k; ++dj; }
            for (; k + 1 < len; k += 2, dj += 2) {
                uint2 p; p.x = staging[i + k]; p.y = staging[i + k + 1];
                *reinterpret_cast<uint2*>(&ebuf[dj]) = p;
            }
            if (k < len) ebuf[dj] = staging[i + k];
        }
        i = runEnd;
    }
}

// ---------------------------------------------------------------------------
// k_gather (r11-verified, unchanged): phases A-C, no MFMA ballast, high
// residency. Writes 64 fp8 mean rows into the bucket's OWN dead ebuf slot.
// LDS 10.8 KB.
// ---------------------------------------------------------------------------
__global__ __launch_bounds__(256, 6)
void k_gather(const unsigned char* __restrict__ xq,
              const unsigned int* __restrict__ gcur,
              unsigned int* __restrict__ ebuf)
{
    __shared__ unsigned int ew[BCAP];          // 10240 B sorted edge words
    __shared__ unsigned int hcnt[64];
    __shared__ unsigned int hstart[65];

    const int t    = threadIdx.x;
    const int w    = t >> 6;
    const int lane = t & 63;
    const int b    = blockIdx.x;

    const unsigned int cntu = gcur[b];
    const int count = (int)(cntu < (unsigned)BCAP ? cntu : (unsigned)BCAP);
    const size_t bb = (size_t)b * BCAP;

    // A: register-stage + zero histogram (ebuf[b] is dead after this)
    unsigned int wreg[10];
    #pragma unroll
    for (int k = 0; k < 10; ++k) {
        const int i = t + k * 256;
        wreg[k] = (i < count) ? ebuf[bb + i] : 0xFFFFFFFFu;
    }
    if (t < 64) hcnt[t] = 0u;
    __syncthreads();

    // B1: histogram (one LDS atomic per edge)
    #pragma unroll
    for (int k = 0; k < 10; ++k)
        if (wreg[k] != 0xFFFFFFFFu) atomicAdd(&hcnt[wreg[k] >> 17], 1u);
    __syncthreads();

    // B2: wave-0 inclusive scan -> hstart
    if (t < 64) {
        unsigned int p = hcnt[t];
        #pragma unroll
        for (int d = 1; d < 64; d <<= 1) {
            const unsigned int v = __shfl_up(p, d, 64);
            if (lane >= d) p += v;
        }
        hstart[t + 1] = p;
        if (t == 0) hstart[0] = 0u;
    }
    __syncthreads();
    if (t < 64) hcnt[t] = hstart[t];
    __syncthreads();

    // B3: scatter into sorted ew[]
    #pragma unroll
    for (int k = 0; k < 10; ++k) {
        const unsigned int wv = wreg[k];
        if (wv != 0xFFFFFFFFu) {
            const unsigned int pos = atomicAdd(&hcnt[wv >> 17], 1u);
            ew[pos] = wv;
        }
    }
    __syncthreads();

    // C: half-wave dual-row gather (r8-verified), fp8 mean -> ebuf slot
    const int half = lane >> 5;
    const int hl   = lane & 31;
    const size_t boff = (size_t)(hl << 2);

    for (int i = 0; i < 16; ++i) {
        const int n = w * 16 + i;
        const int s = (int)hstart[n];
        const int e = (int)hstart[n + 1];
        const int dg = e - s;
        float a0 = 0.f, a1 = 0.f, a2 = 0.f, a3 = 0.f;
        int c = s;
        for (; c + 8 <= e; c += 8) {
            unsigned int u[4];
            #pragma unroll
            for (int j = 0; j < 4; ++j) {
                const unsigned int wj = ew[c + 2 * j + half];
                u[j] = *reinterpret_cast<const unsigned int*>(
                    xq + ((size_t)(wj & 0x1FFFFu) << 7) + boff);
            }
            #pragma unroll
            for (int j = 0; j < 4; ++j) {
                const f32x2 p = __builtin_amdgcn_cvt_pk_f32_fp8(u[j], false);
                const f32x2 q = __builtin_amdgcn_cvt_pk_f32_fp8(u[j], true);
                a0 += p[0]; a1 += p[1]; a2 += q[0]; a3 += q[1];
            }
        }
        for (; c + 2 <= e; c += 2) {
            const unsigned int w0 = ew[c + half];
            const unsigned int u0 = *reinterpret_cast<const unsigned int*>(
                xq + ((size_t)(w0 & 0x1FFFFu) << 7) + boff);
            const f32x2 p = __builtin_amdgcn_cvt_pk_f32_fp8(u0, false);
            const f32x2 q = __builtin_amdgcn_cvt_pk_f32_fp8(u0, true);
            a0 += p[0]; a1 += p[1]; a2 += q[0]; a3 += q[1];
        }
        if (c < e && half == 0) {              // final odd edge, half 0 only
            const unsigned int w0 = ew[c];
            const unsigned int u0 = *reinterpret_cast<const unsigned int*>(
                xq + ((size_t)(w0 & 0x1FFFFu) << 7) + boff);
            const f32x2 p = __builtin_amdgcn_cvt_pk_f32_fp8(u0, false);
            const f32x2 q = __builtin_amdgcn_cvt_pk_f32_fp8(u0, true);
            a0 += p[0]; a1 += p[1]; a2 += q[0]; a3 += q[1];
        }
        a0 += __shfl_xor(a0, 32, 64);
        a1 += __shfl_xor(a1, 32, 64);
        a2 += __shfl_xor(a2, 32, 64);
        a3 += __shfl_xor(a3, 32, 64);
        const float inv = 1.0f / (float)(dg > 1 ? dg : 1);
        if (half == 0) {
            int pk = __builtin_amdgcn_cvt_pk_fp8_f32(a0 * inv, a1 * inv, 0, false);
            pk     = __builtin_amdgcn_cvt_pk_fp8_f32(a2 * inv, a3 * inv, pk, true);
            ebuf[bb + (unsigned)(n << 5) + (unsigned)hl] = (unsigned)pk;  // 128B/row
        }
    }
}

// ---------------------------------------------------------------------------
// k_gemm (r11 core): stage 64 fp8 mean rows into LDS; root path reads x
// fp32 DIRECTLY and converts to bf16 in registers (xb copy eliminated).
// MFMA GEMM [mean|x]@[Wl;Wr]+b -> LayerNorm -> exact GELU.
// ---------------------------------------------------------------------------
__global__ __launch_bounds__(256)
void k_gemm(const float* __restrict__ x,
            const unsigned int* __restrict__ ebuf,
            const unsigned short* __restrict__ wf,
            const float* __restrict__ bl,
            const float* __restrict__ gamma,
            const float* __restrict__ beta,
            float* __restrict__ out)
{
    __shared__ unsigned char smean[64][136];   // 8704 B fp8 mean rows

    const int t    = threadIdx.x;
    const int w    = t >> 6;
    const int lane = t & 63;
    const int b    = blockIdx.x;
    const int nodeBase = b * 64;

    // stage: 2048 uints, coalesced global read -> strided LDS write
    const unsigned int* gm = ebuf + (size_t)b * BCAP;
    #pragma unroll
    for (int k = 0; k < 8; ++k) {
        const int idx = k * 256 + t;          // 0..2047
        const int row = idx >> 5;
        const int c4  = (idx & 31) << 2;
        *reinterpret_cast<unsigned int*>(&smean[row][c4]) = gm[idx];
    }
    __syncthreads();

    // MFMA GEMM, K = 256 = [mean(128) | x(128)] (verified r4/r10/r11)
    const int row  = lane & 15;
    const int kgrp = lane >> 4;
    const int node_r = nodeBase + w * 16 + row;
    const float* xp = x + ((size_t)(node_r < NN ? node_r : NN - 1) << 7);

    f32x4 accr[8];
    const f32x4 zero = {0.f, 0.f, 0.f, 0.f};
    #pragma unroll
    for (int q = 0; q < 8; ++q) accr[q] = zero;

    #pragma unroll
    for (int kt = 0; kt < 8; ++kt) {
        bf16x8 a;
        if (kt < 4) {
            const uint2 m8 = *reinterpret_cast<const uint2*>(
                &smean[w * 16 + row][kt * 32 + kgrp * 8]);
            a = fp8x8_to_bf16x8(m8.x, m8.y);
        } else {
            const float4 va = *reinterpret_cast<const float4*>(
                xp + (kt - 4) * 32 + kgrp * 8);
            const float4 vb = *reinterpret_cast<const float4*>(
                xp + (kt - 4) * 32 + kgrp * 8 + 4);
            union { unsigned int wd[4]; bf16x8 v; } r;
            r.wd[0] = (unsigned)f2bf(va.x) | ((unsigned)f2bf(va.y) << 16);
            r.wd[1] = (unsigned)f2bf(va.z) | ((unsigned)f2bf(va.w) << 16);
            r.wd[2] = (unsigned)f2bf(vb.x) | ((unsigned)f2bf(vb.y) << 16);
            r.wd[3] = (unsigned)f2bf(vb.z) | ((unsigned)f2bf(vb.w) << 16);
            a = r.v;
        }
        #pragma unroll
        for (int q = 0; q < 8; ++q) {
            const bf16x8 bfrag = *reinterpret_cast<const bf16x8*>(
                wf + (((kt * 8 + q) * 64 + lane) << 3));
            accr[q] = __builtin_amdgcn_mfma_f32_16x16x32_bf16(a, bfrag, accr[q], 0, 0, 0);
        }
    }

    // bias + LayerNorm + exact GELU + store
    const int col = lane & 15;
    float gv[8], bev[8], blv[8];
    #pragma unroll
    for (int q = 0; q < 8; ++q) {
        gv[q]  = gamma[q * 16 + col];
        bev[q] = beta[q * 16 + col];
        blv[q] = bl[q * 16 + col];
    }
    const float k2 = 0.70710678118654752f;
    #pragma unroll
    for (int r = 0; r < 4; ++r) {
        float p = 0.f, p2 = 0.f;
        #pragma unroll
        for (int q = 0; q < 8; ++q) {
            const float h = accr[q][r] + blv[q];
            p += h; p2 += h * h;
        }
        #pragma unroll
        for (int m = 1; m <= 8; m <<= 1) {
            p  += __shfl_xor(p,  m, 64);
            p2 += __shfl_xor(p2, m, 64);
        }
        const float mu   = p * (1.0f / 128.0f);
        const float var  = p2 * (1.0f / 128.0f) - mu * mu;
        const float rstd = rsqrtf(var + 1e-5f);
        const int node = nodeBase + w * 16 + kgrp * 4 + r;
        if (node < NN) {
            #pragma unroll
            for (int q = 0; q < 8; ++q) {
                const float h = accr[q][r] + blv[q];
                const float y = (h - mu) * rstd * gv[q] + bev[q];
                out[(size_t)node * D + q * 16 + col] = 0.5f * y * (1.0f + erff(y * k2));
            }
        }
    }
}

extern "C" void kernel_launch(void* const* d_in, const int* in_sizes, int n_in,
                              void* d_out, int out_size, void* d_ws, size_t ws_size,
                              hipStream_t stream)
{
    const float* x     = (const float*)d_in[0];
    const int*   ei    = (const int*)d_in[1];
    const float* Wl    = (const float*)d_in[2];
    const float* bl    = (const float*)d_in[3];
    const float* Wr    = (const float*)d_in[4];
    const float* gamma = (const float*)d_in[5];
    const float* beta  = (const float*)d_in[6];
    float* out = (float*)d_out;

    // ws layout: gcur 8K | ebuf 16.0M | xq 12.8M | wf 64K  (~28.9 MB)
    char* wsp = (char*)d_ws;
    unsigned int*   gcur = (unsigned int*)(wsp + 0);
    unsigned int*   ebuf = (unsigned int*)(wsp + 32768);
    unsigned char*  xq   = (unsigned char*)(wsp + 16037888);
    unsigned short* wf   = (unsigned short*)(wsp + 28837888);

    hipMemsetAsync(gcur, 0, NBUKP * sizeof(unsigned int), stream);

    k_all<<<PBLK + CBLK + 32, 1024, 0, stream>>>(x, ei, Wl, Wr, xq, wf,
                                                 gcur, ebuf);

    k_gather<<<NBUK, 256, 0, stream>>>(xq, gcur, ebuf);

    k_gemm<<<NBUK, 256, 0, stream>>>(x, ebuf, wf, bl, gamma, beta, out);
}